// Round 2
// baseline (818.083 us; speedup 1.0000x reference)
//
#include <hip/hip_runtime.h>
#include <hip/hip_bf16.h>

// GNN: h = x@We^T + be; 2x { h = relu(segsum(h[col],row) @ W^T + b) };
// out = relu(mean(h,1) @ Wc1^T + bc1) @ Wc2^T + bc2   (scalar fp32)
//
// Restructure: relu((A h) W^T + b) == relu(A (h W^T) + b)  (A = sparse adj).
// R2: GEMM switched to 32x32x16 MFMA (higher ceiling, fewer instrs) with
// double-buffered LDS (1 barrier/iter, prefetch issued after the barrier so
// the vmcnt drain covers loads issued one full iteration earlier) and an
// XOR chunk swizzle to keep LDS reads at 8-way (naive 32x32 reads are 16-way).

#define N_NODES 4096
#define IN_DIM_ 512
#define HID_ 4096
#define NEDGE 65536

typedef __bf16 bf16x8 __attribute__((ext_vector_type(8)));
typedef float f32x16 __attribute__((ext_vector_type(16)));
typedef unsigned short u16x8 __attribute__((ext_vector_type(8)));

__device__ __forceinline__ unsigned short f2bf(float f) {
  unsigned u = __float_as_uint(f);
  return (unsigned short)((u + 0x7fffu + ((u >> 16) & 1u)) >> 16);  // RNE
}
__device__ __forceinline__ float bf2f(unsigned short h) {
  return __uint_as_float((unsigned)h << 16);
}

// ---------------- fp32 -> bf16, 8 elems/thread ----------------
__global__ __launch_bounds__(256) void cvt_bf16(const float* __restrict__ in,
                                                unsigned short* __restrict__ out,
                                                int n) {
  int i = (blockIdx.x * 256 + threadIdx.x) * 8;
  if (i >= n) return;
  const float4 a = *(const float4*)(in + i);
  const float4 b = *(const float4*)(in + i + 4);
  u16x8 r;
  r[0] = f2bf(a.x); r[1] = f2bf(a.y); r[2] = f2bf(a.z); r[3] = f2bf(a.w);
  r[4] = f2bf(b.x); r[5] = f2bf(b.y); r[6] = f2bf(b.z); r[7] = f2bf(b.w);
  *(u16x8*)(out + i) = r;
}

// ---------------- CSR build ----------------
__global__ __launch_bounds__(256) void zero_i32(int* __restrict__ p, int n) {
  int i = blockIdx.x * 256 + threadIdx.x;
  if (i < n) p[i] = 0;
}

__global__ __launch_bounds__(256) void hist_rows(const int* __restrict__ row,
                                                 int* __restrict__ counts) {
  int e = blockIdx.x * 256 + threadIdx.x;
  if (e < NEDGE) atomicAdd(&counts[row[e]], 1);
}

// exclusive scan of counts[4096] -> starts[4097]; single block of 1024 threads
__global__ __launch_bounds__(1024) void scan4096(const int* __restrict__ counts,
                                                 int* __restrict__ starts) {
  __shared__ int sa[1024], sb[1024];
  const int t = threadIdx.x;
  const int c0 = counts[t * 4], c1 = counts[t * 4 + 1],
            c2 = counts[t * 4 + 2], c3 = counts[t * 4 + 3];
  const int local = c0 + c1 + c2 + c3;
  sa[t] = local;
  __syncthreads();
  int* src = sa; int* dst = sb;
  for (int off = 1; off < 1024; off <<= 1) {
    int v = src[t];
    if (t >= off) v += src[t - off];
    dst[t] = v;
    __syncthreads();
    int* tmp = src; src = dst; dst = tmp;
  }
  const int excl = (t == 0) ? 0 : src[t - 1];
  starts[t * 4]     = excl;
  starts[t * 4 + 1] = excl + c0;
  starts[t * 4 + 2] = excl + c0 + c1;
  starts[t * 4 + 3] = excl + c0 + c1 + c2;
  if (t == 1023) starts[4096] = excl + local;
}

__global__ __launch_bounds__(256) void fill_adj(const int* __restrict__ row,
                                                const int* __restrict__ col,
                                                const int* __restrict__ starts,
                                                int* __restrict__ cursor,
                                                int* __restrict__ adj) {
  int e = blockIdx.x * 256 + threadIdx.x;
  if (e >= NEDGE) return;
  int r = row[e];
  int p = atomicAdd(&cursor[r], 1);
  adj[starts[r] + p] = col[e];
}

// ---------------- bf16 GEMM: C[M,N] = A[M,K] @ B[N,K]^T (+bias) ----------------
// 128x128 tile, BK=32, 4 waves each 64x64 (2x2 of 32x32x16 MFMA),
// double-buffered LDS (2x16KB), global_load_lds width=16, XOR chunk swizzle.
// LDS layout: row stride 64B; row r, 16B-chunk lc holds global chunk lc^(r&3).
__global__ __launch_bounds__(256) void gemm_bt(const unsigned short* __restrict__ A,
                                               const unsigned short* __restrict__ B,
                                               unsigned short* __restrict__ C,
                                               int M, int N, int K,
                                               const float* __restrict__ bias) {
  __shared__ unsigned short As[2 * 128 * 32];
  __shared__ unsigned short Bs[2 * 128 * 32];
  const int t = threadIdx.x;
  const int bm = blockIdx.x * 128, bn = blockIdx.y * 128;
  const int wave = t >> 6, lane = t & 63;
  const int wm = (wave >> 1) * 64, wn = (wave & 1) * 64;
  const int m32 = lane & 31, half = lane >> 5;  // A/B layout: m=lane&31, k=half*8+j

  f32x16 acc[2][2] = {};

  // staging: thread t loads 16 B; global chunk = (t&3)^(srow&3)  (XOR swizzle)
  const int srow = t >> 2;                   // 0..63
  const int gsc = (t & 3) ^ (srow & 3);      // swizzled source chunk
  const unsigned short* Ag0 = A + (size_t)(bm + srow) * K + gsc * 8;
  const unsigned short* Ag1 = A + (size_t)(bm + 64 + srow) * K + gsc * 8;
  const unsigned short* Bg0 = B + (size_t)(bn + srow) * K + gsc * 8;
  const unsigned short* Bg1 = B + (size_t)(bn + 64 + srow) * K + gsc * 8;
  char* AsB = (char*)As;
  char* BsB = (char*)Bs;

  auto stage = [&](int buf, int kb) {
    char* lA = AsB + buf * 8192 + t * 16;
    char* lB = BsB + buf * 8192 + t * 16;
    __builtin_amdgcn_global_load_lds(
        (const __attribute__((address_space(1))) void*)(Ag0 + kb),
        (__attribute__((address_space(3))) void*)lA, 16, 0, 0);
    __builtin_amdgcn_global_load_lds(
        (const __attribute__((address_space(1))) void*)(Ag1 + kb),
        (__attribute__((address_space(3))) void*)(lA + 4096), 16, 0, 0);
    __builtin_amdgcn_global_load_lds(
        (const __attribute__((address_space(1))) void*)(Bg0 + kb),
        (__attribute__((address_space(3))) void*)lB, 16, 0, 0);
    __builtin_amdgcn_global_load_lds(
        (const __attribute__((address_space(1))) void*)(Bg1 + kb),
        (__attribute__((address_space(3))) void*)(lB + 4096), 16, 0, 0);
  };

  // read offsets (loop-invariant): a-frag (rt, ks): row = wm+rt*32+m32,
  // global chunk = half + 2*ks, LDS chunk = gc ^ (m32&3)
  const int sw = m32 & 3;
  int aoff[2][2], boff[2][2];
#pragma unroll
  for (int rt = 0; rt < 2; ++rt)
#pragma unroll
    for (int ks = 0; ks < 2; ++ks) {
      aoff[rt][ks] = (wm + rt * 32 + m32) * 64 + ((half + 2 * ks) ^ sw) * 16;
      boff[rt][ks] = (wn + rt * 32 + m32) * 64 + ((half + 2 * ks) ^ sw) * 16;
    }

  const int NI = K / 32;
  stage(0, 0);
  for (int i = 0; i < NI; ++i) {
    const int buf = i & 1;
    __syncthreads();  // drains stage(buf) (issued 1 iter ago) + guards buf^1 reuse
    if (i + 1 < NI) stage(buf ^ 1, (i + 1) * 32);
    const char* ab = AsB + buf * 8192;
    const char* bb = BsB + buf * 8192;
#pragma unroll
    for (int ks = 0; ks < 2; ++ks) {
      bf16x8 a0 = *(const bf16x8*)(ab + aoff[0][ks]);
      bf16x8 a1 = *(const bf16x8*)(ab + aoff[1][ks]);
      bf16x8 b0 = *(const bf16x8*)(bb + boff[0][ks]);
      bf16x8 b1 = *(const bf16x8*)(bb + boff[1][ks]);
      acc[0][0] = __builtin_amdgcn_mfma_f32_32x32x16_bf16(a0, b0, acc[0][0], 0, 0, 0);
      acc[0][1] = __builtin_amdgcn_mfma_f32_32x32x16_bf16(a0, b1, acc[0][1], 0, 0, 0);
      acc[1][0] = __builtin_amdgcn_mfma_f32_32x32x16_bf16(a1, b0, acc[1][0], 0, 0, 0);
      acc[1][1] = __builtin_amdgcn_mfma_f32_32x32x16_bf16(a1, b1, acc[1][1], 0, 0, 0);
    }
  }

  // C/D layout (m74/m101): col = lane&31, row = (reg&3) + 8*(reg>>2) + 4*(lane>>5)
#pragma unroll
  for (int rt = 0; rt < 2; ++rt) {
#pragma unroll
    for (int ct = 0; ct < 2; ++ct) {
      const int col = bn + wn + ct * 32 + m32;
      const float bv = bias ? bias[col] : 0.0f;
      const int rbase = bm + wm + rt * 32 + 4 * half;
#pragma unroll
      for (int i = 0; i < 16; ++i) {
        const int row = rbase + (i & 3) + 8 * (i >> 2);
        C[(size_t)row * N + col] = f2bf(acc[rt][ct][i] + bv);
      }
    }
  }
}

// ---------------- aggregation: h[node] = relu(sum_{c in adj(node)} g[c] + b) ----------------
// grid (2, N_NODES): 2048 feats per block, 8 per thread, fp32 accumulate.
// Neighbor loop unrolled x4 for memory ILP (4 gathers in flight).
__global__ __launch_bounds__(256) void aggr_bias_relu(
    const unsigned short* __restrict__ g, const int* __restrict__ starts,
    const int* __restrict__ adj, const float* __restrict__ bias,
    unsigned short* __restrict__ hout) {
  const int node = blockIdx.y;
  const int f0 = blockIdx.x * 2048 + threadIdx.x * 8;
  float acc[8] = {0, 0, 0, 0, 0, 0, 0, 0};
  const int s = starts[node], e = starts[node + 1];
  int j = s;
  for (; j + 4 <= e; j += 4) {
    const int c0 = adj[j], c1 = adj[j + 1], c2 = adj[j + 2], c3 = adj[j + 3];
    u16x8 v0 = *(const u16x8*)(g + (size_t)c0 * HID_ + f0);
    u16x8 v1 = *(const u16x8*)(g + (size_t)c1 * HID_ + f0);
    u16x8 v2 = *(const u16x8*)(g + (size_t)c2 * HID_ + f0);
    u16x8 v3 = *(const u16x8*)(g + (size_t)c3 * HID_ + f0);
#pragma unroll
    for (int i = 0; i < 8; ++i)
      acc[i] += (bf2f(v0[i]) + bf2f(v1[i])) + (bf2f(v2[i]) + bf2f(v3[i]));
  }
  for (; j < e; ++j) {
    const int c = adj[j];
    u16x8 v = *(const u16x8*)(g + (size_t)c * HID_ + f0);
#pragma unroll
    for (int i = 0; i < 8; ++i) acc[i] += bf2f(v[i]);
  }
  const float4 b0 = *(const float4*)(bias + f0);
  const float4 b1 = *(const float4*)(bias + f0 + 4);
  const float bb[8] = {b0.x, b0.y, b0.z, b0.w, b1.x, b1.y, b1.z, b1.w};
  u16x8 r;
#pragma unroll
  for (int i = 0; i < 8; ++i) r[i] = f2bf(fmaxf(acc[i] + bb[i], 0.0f));
  *(u16x8*)(hout + (size_t)node * HID_ + f0) = r;
}

// ---------------- hm[row] = mean(h[row,:]) ----------------
__global__ __launch_bounds__(256) void row_mean(const unsigned short* __restrict__ h,
                                                float* __restrict__ hm) {
  const int row = blockIdx.x, t = threadIdx.x;
  const u16x8* p = (const u16x8*)(h + (size_t)row * HID_);
  u16x8 v1 = p[t], v2 = p[t + 256];
  float s = 0.f;
#pragma unroll
  for (int i = 0; i < 8; ++i) s += bf2f(v1[i]) + bf2f(v2[i]);
  for (int off = 32; off > 0; off >>= 1) s += __shfl_down(s, off);
  __shared__ float ws[4];
  if ((t & 63) == 0) ws[t >> 6] = s;
  __syncthreads();
  if (t == 0) hm[row] = (ws[0] + ws[1] + ws[2] + ws[3]) * (1.0f / (float)HID_);
}

// ---------------- z[j] = relu(Wc1[j,:].hm + bc1[j]), one wave per j ----------------
__global__ __launch_bounds__(256) void clf1(const float* __restrict__ Wc1,
                                            const float* __restrict__ bc1,
                                            const float* __restrict__ hm,
                                            float* __restrict__ z) {
  const int wave = threadIdx.x >> 6, lane = threadIdx.x & 63;
  const int j = blockIdx.x * 4 + wave;
  const float* w = Wc1 + (size_t)j * HID_;
  float s = 0.f;
  for (int i = lane; i < HID_; i += 64) s += w[i] * hm[i];
  for (int off = 32; off > 0; off >>= 1) s += __shfl_down(s, off);
  if (lane == 0) z[j] = fmaxf(s + bc1[j], 0.0f);
}

// ---------------- out = Wc2.z + bc2 ----------------
__global__ __launch_bounds__(256) void clf2(const float* __restrict__ Wc2,
                                            const float* __restrict__ bc2,
                                            const float* __restrict__ z,
                                            float* __restrict__ out) {
  const int t = threadIdx.x;
  float s = 0.f;
  for (int i = t; i < HID_ / 2; i += 256) s += z[i] * Wc2[i];
  for (int off = 32; off > 0; off >>= 1) s += __shfl_down(s, off);
  __shared__ float ws[4];
  if ((t & 63) == 0) ws[t >> 6] = s;
  __syncthreads();
  if (t == 0) out[0] = ws[0] + ws[1] + ws[2] + ws[3] + bc2[0];
}

extern "C" void kernel_launch(void* const* d_in, const int* in_sizes, int n_in,
                              void* d_out, int out_size, void* d_ws, size_t ws_size,
                              hipStream_t stream) {
  (void)in_sizes; (void)n_in; (void)out_size; (void)ws_size;
  const float* x       = (const float*)d_in[0];
  const int*   edge    = (const int*)d_in[1];
  const int*   row     = edge;
  const int*   col     = edge + NEDGE;
  const float* W_embed = (const float*)d_in[2];
  const float* b_embed = (const float*)d_in[3];
  const float* W1      = (const float*)d_in[4];
  const float* b1      = (const float*)d_in[5];
  const float* W2      = (const float*)d_in[6];
  const float* b2      = (const float*)d_in[7];
  const float* Wc1     = (const float*)d_in[8];
  const float* bc1     = (const float*)d_in[9];
  const float* Wc2     = (const float*)d_in[10];
  const float* bc2     = (const float*)d_in[11];
  float* out = (float*)d_out;

  char* ws = (char*)d_ws;
  size_t off = 0;
  auto alloc = [&](size_t bytes) {
    char* p = ws + off;
    off += (bytes + 255) & ~(size_t)255;
    return p;
  };
  unsigned short* xb  = (unsigned short*)alloc((size_t)N_NODES * IN_DIM_ * 2);
  unsigned short* web = (unsigned short*)alloc((size_t)HID_ * IN_DIM_ * 2);
  unsigned short* w1b = (unsigned short*)alloc((size_t)HID_ * HID_ * 2);
  unsigned short* w2b = (unsigned short*)alloc((size_t)HID_ * HID_ * 2);
  unsigned short* h   = (unsigned short*)alloc((size_t)N_NODES * HID_ * 2);
  unsigned short* g   = (unsigned short*)alloc((size_t)N_NODES * HID_ * 2);
  int* counts = (int*)alloc(N_NODES * 4);
  int* cursor = (int*)alloc(N_NODES * 4);
  int* starts = (int*)alloc((N_NODES + 1) * 4);
  int* adj    = (int*)alloc(NEDGE * 4);
  float* hm   = (float*)alloc(N_NODES * 4);
  float* z    = (float*)alloc((HID_ / 2) * 4);

  // CSR build (ws is re-poisoned each call -> must zero)
  zero_i32<<<16, 256, 0, stream>>>(counts, N_NODES);
  zero_i32<<<16, 256, 0, stream>>>(cursor, N_NODES);
  hist_rows<<<NEDGE / 256, 256, 0, stream>>>(row, counts);
  scan4096<<<1, 1024, 0, stream>>>(counts, starts);
  fill_adj<<<NEDGE / 256, 256, 0, stream>>>(row, col, starts, cursor, adj);

  // fp32 -> bf16 inputs/weights
  cvt_bf16<<<(N_NODES * IN_DIM_ / 8) / 256, 256, 0, stream>>>(x, xb, N_NODES * IN_DIM_);
  cvt_bf16<<<(HID_ * IN_DIM_ / 8) / 256, 256, 0, stream>>>(W_embed, web, HID_ * IN_DIM_);
  cvt_bf16<<<(HID_ * HID_ / 8) / 256, 256, 0, stream>>>(W1, w1b, HID_ * HID_);
  cvt_bf16<<<(HID_ * HID_ / 8) / 256, 256, 0, stream>>>(W2, w2b, HID_ * HID_);

  // h = x @ We^T + be
  gemm_bt<<<dim3(32, 32), 256, 0, stream>>>(xb, web, h, N_NODES, HID_, IN_DIM_, b_embed);
  // layer 1: g = h @ W1^T ; h = relu(A g + b1)
  gemm_bt<<<dim3(32, 32), 256, 0, stream>>>(h, w1b, g, N_NODES, HID_, HID_, nullptr);
  aggr_bias_relu<<<dim3(2, N_NODES), 256, 0, stream>>>(g, starts, adj, b1, h);
  // layer 2
  gemm_bt<<<dim3(32, 32), 256, 0, stream>>>(h, w2b, g, N_NODES, HID_, HID_, nullptr);
  aggr_bias_relu<<<dim3(2, N_NODES), 256, 0, stream>>>(g, starts, adj, b2, h);
  // classifier tail
  row_mean<<<N_NODES, 256, 0, stream>>>(h, hm);
  clf1<<<(HID_ / 2) / 4, 256, 0, stream>>>(Wc1, bc1, hm, z);
  clf2<<<1, 256, 0, stream>>>(Wc2, bc2, z, out);
}

// Round 3
// 789.384 us; speedup vs baseline: 1.0364x; 1.0364x over previous
//
#include <hip/hip_runtime.h>
#include <hip/hip_bf16.h>

// GNN: h = x@We^T + be; 2x { h = relu(segsum(h[col],row) @ W^T + b) };
// out = relu(mean(h,1) @ Wc1^T + bc1) @ Wc2^T + bc2   (scalar fp32)
//
// Restructure: relu((A h) W^T + b) == relu(A (h W^T) + b)  (A = sparse adj).
// R3: GEMM back to R1-exact 16x16x32 structure (R2's XOR swizzle tripled LDS
// bank conflicts -> reverted; dbuf neutral -> reverted). The two K=4096 GEMMs
// run in fp8 e4m3 (static scales: act x8, weights x256, epilogue /2048 fp32)
// halving staging + LDS-read bytes per FLOP. Embed GEMM stays bf16.

#define N_NODES 4096
#define IN_DIM_ 512
#define HID_ 4096
#define NEDGE 65536

typedef __bf16 bf16x8 __attribute__((ext_vector_type(8)));
typedef float f32x4 __attribute__((ext_vector_type(4)));
typedef unsigned short u16x8 __attribute__((ext_vector_type(8)));

#define ACT_SCALE 8.0f
#define W_SCALE 256.0f
#define INV_GEMM_SCALE (1.0f / 2048.0f)

__device__ __forceinline__ unsigned short f2bf(float f) {
  unsigned u = __float_as_uint(f);
  return (unsigned short)((u + 0x7fffu + ((u >> 16) & 1u)) >> 16);  // RNE
}
__device__ __forceinline__ float bf2f(unsigned short h) {
  return __uint_as_float((unsigned)h << 16);
}
__device__ __forceinline__ unsigned char f2fp8(float f) {
  int w = __builtin_amdgcn_cvt_pk_fp8_f32(f, f, 0, false);  // OCP e4m3 on gfx950
  return (unsigned char)(w & 0xff);
}

// ---------------- fp32 -> bf16, 8 elems/thread ----------------
__global__ __launch_bounds__(256) void cvt_bf16(const float* __restrict__ in,
                                                unsigned short* __restrict__ out,
                                                int n) {
  int i = (blockIdx.x * 256 + threadIdx.x) * 8;
  if (i >= n) return;
  const float4 a = *(const float4*)(in + i);
  const float4 b = *(const float4*)(in + i + 4);
  u16x8 r;
  r[0] = f2bf(a.x); r[1] = f2bf(a.y); r[2] = f2bf(a.z); r[3] = f2bf(a.w);
  r[4] = f2bf(b.x); r[5] = f2bf(b.y); r[6] = f2bf(b.z); r[7] = f2bf(b.w);
  *(u16x8*)(out + i) = r;
}

// ---------------- fp32 -> fp8 e4m3 (x scale), 8 elems/thread ----------------
__global__ __launch_bounds__(256) void cvt_fp8(const float* __restrict__ in,
                                               unsigned char* __restrict__ out,
                                               int n, float scale) {
  int i = (blockIdx.x * 256 + threadIdx.x) * 8;
  if (i >= n) return;
  const float4 a = *(const float4*)(in + i);
  const float4 b = *(const float4*)(in + i + 4);
  int w0 = __builtin_amdgcn_cvt_pk_fp8_f32(a.x * scale, a.y * scale, 0, false);
  w0 = __builtin_amdgcn_cvt_pk_fp8_f32(a.z * scale, a.w * scale, w0, true);
  int w1 = __builtin_amdgcn_cvt_pk_fp8_f32(b.x * scale, b.y * scale, 0, false);
  w1 = __builtin_amdgcn_cvt_pk_fp8_f32(b.z * scale, b.w * scale, w1, true);
  *(int2*)(out + i) = make_int2(w0, w1);
}

// ---------------- CSR build ----------------
__global__ __launch_bounds__(256) void zero_i32(int* __restrict__ p, int n) {
  int i = blockIdx.x * 256 + threadIdx.x;
  if (i < n) p[i] = 0;
}

__global__ __launch_bounds__(256) void hist_rows(const int* __restrict__ row,
                                                 int* __restrict__ counts) {
  int e = blockIdx.x * 256 + threadIdx.x;
  if (e < NEDGE) atomicAdd(&counts[row[e]], 1);
}

// exclusive scan of counts[4096] -> starts[4097]; single block of 1024 threads
__global__ __launch_bounds__(1024) void scan4096(const int* __restrict__ counts,
                                                 int* __restrict__ starts) {
  __shared__ int sa[1024], sb[1024];
  const int t = threadIdx.x;
  const int c0 = counts[t * 4], c1 = counts[t * 4 + 1],
            c2 = counts[t * 4 + 2], c3 = counts[t * 4 + 3];
  const int local = c0 + c1 + c2 + c3;
  sa[t] = local;
  __syncthreads();
  int* src = sa; int* dst = sb;
  for (int off = 1; off < 1024; off <<= 1) {
    int v = src[t];
    if (t >= off) v += src[t - off];
    dst[t] = v;
    __syncthreads();
    int* tmp = src; src = dst; dst = tmp;
  }
  const int excl = (t == 0) ? 0 : src[t - 1];
  starts[t * 4]     = excl;
  starts[t * 4 + 1] = excl + c0;
  starts[t * 4 + 2] = excl + c0 + c1;
  starts[t * 4 + 3] = excl + c0 + c1 + c2;
  if (t == 1023) starts[4096] = excl + local;
}

__global__ __launch_bounds__(256) void fill_adj(const int* __restrict__ row,
                                                const int* __restrict__ col,
                                                const int* __restrict__ starts,
                                                int* __restrict__ cursor,
                                                int* __restrict__ adj) {
  int e = blockIdx.x * 256 + threadIdx.x;
  if (e >= NEDGE) return;
  int r = row[e];
  int p = atomicAdd(&cursor[r], 1);
  adj[starts[r] + p] = col[e];
}

// ------- bf16 GEMM (embed): C_fp8 = fp8(ACT_SCALE*(A@B^T + bias)) -------
// R1-exact structure: 128x128 tile, BK=32, 4 waves 64x64 (4x4 16x16x32 MFMA).
__global__ __launch_bounds__(256) void gemm_bt_f8out(
    const unsigned short* __restrict__ A, const unsigned short* __restrict__ B,
    unsigned char* __restrict__ C, int M, int N, int K,
    const float* __restrict__ bias) {
  __shared__ unsigned short As[128 * 32];
  __shared__ unsigned short Bs[128 * 32];
  const int t = threadIdx.x;
  const int bm = blockIdx.x * 128, bn = blockIdx.y * 128;
  const int wave = t >> 6, lane = t & 63;
  const int wm = (wave >> 1) * 64, wn = (wave & 1) * 64;
  const int m16 = lane & 15, quad = lane >> 4;

  f32x4 acc[4][4] = {};

  const int srow = t >> 2;
  const int scol = (t & 3) * 8;
  const unsigned short* Ag0 = A + (size_t)(bm + srow) * K + scol;
  const unsigned short* Ag1 = A + (size_t)(bm + 64 + srow) * K + scol;
  const unsigned short* Bg0 = B + (size_t)(bn + srow) * K + scol;
  const unsigned short* Bg1 = B + (size_t)(bn + 64 + srow) * K + scol;
  char* AsB = (char*)As;
  char* BsB = (char*)Bs;
  char* lA0 = AsB + t * 16;
  char* lA1 = AsB + 4096 + t * 16;
  char* lB0 = BsB + t * 16;
  char* lB1 = BsB + 4096 + t * 16;

  for (int kb = 0; kb < K; kb += 32) {
    __builtin_amdgcn_global_load_lds(
        (const __attribute__((address_space(1))) void*)(Ag0 + kb),
        (__attribute__((address_space(3))) void*)lA0, 16, 0, 0);
    __builtin_amdgcn_global_load_lds(
        (const __attribute__((address_space(1))) void*)(Ag1 + kb),
        (__attribute__((address_space(3))) void*)lA1, 16, 0, 0);
    __builtin_amdgcn_global_load_lds(
        (const __attribute__((address_space(1))) void*)(Bg0 + kb),
        (__attribute__((address_space(3))) void*)lB0, 16, 0, 0);
    __builtin_amdgcn_global_load_lds(
        (const __attribute__((address_space(1))) void*)(Bg1 + kb),
        (__attribute__((address_space(3))) void*)lB1, 16, 0, 0);
    __syncthreads();

    bf16x8 af[4], bfr[4];
#pragma unroll
    for (int r = 0; r < 4; ++r)
      af[r] = *(const bf16x8*)(AsB + (wm + r * 16 + m16) * 64 + quad * 16);
#pragma unroll
    for (int c = 0; c < 4; ++c)
      bfr[c] = *(const bf16x8*)(BsB + (wn + c * 16 + m16) * 64 + quad * 16);
#pragma unroll
    for (int r = 0; r < 4; ++r)
#pragma unroll
      for (int c = 0; c < 4; ++c)
        acc[r][c] = __builtin_amdgcn_mfma_f32_16x16x32_bf16(af[r], bfr[c],
                                                            acc[r][c], 0, 0, 0);
    __syncthreads();
  }

  // C/D layout (m89/m91): col = lane&15, row = quad*4 + reg
#pragma unroll
  for (int r = 0; r < 4; ++r) {
#pragma unroll
    for (int c = 0; c < 4; ++c) {
      const int row0 = bm + wm + r * 16 + quad * 4;
      const int col = bn + wn + c * 16 + m16;
      const float bv = bias[col];
#pragma unroll
      for (int i = 0; i < 4; ++i) {
        float v = acc[r][c][i] + bv;
        C[(size_t)(row0 + i) * N + col] = f2fp8(ACT_SCALE * v);
      }
    }
  }
}

// ------- fp8 GEMM: C_bf16 = bf16(INV_GEMM_SCALE * (A@B^T)) -------
// Same structure; operands e4m3 (scaled), LDS tiles 4KB each, ds_read b64.
__global__ __launch_bounds__(256) void gemm_fp8(
    const unsigned char* __restrict__ A, const unsigned char* __restrict__ B,
    unsigned short* __restrict__ C, int M, int N, int K) {
  __shared__ unsigned char As[128 * 32];
  __shared__ unsigned char Bs[128 * 32];
  const int t = threadIdx.x;
  const int bm = blockIdx.x * 128, bn = blockIdx.y * 128;
  const int wave = t >> 6, lane = t & 63;
  const int wm = (wave >> 1) * 64, wn = (wave & 1) * 64;
  const int m16 = lane & 15, quad = lane >> 4;

  f32x4 acc[4][4] = {};

  // staging: thread t -> row t>>1 (0..127), 16B chunk t&1
  const int srow = t >> 1;
  const int scol = (t & 1) * 16;
  const unsigned char* Ag = A + (size_t)(bm + srow) * K + scol;
  const unsigned char* Bg = B + (size_t)(bn + srow) * K + scol;
  char* AsB = (char*)As;
  char* BsB = (char*)Bs;
  char* lA = AsB + t * 16;
  char* lB = BsB + t * 16;

  for (int kb = 0; kb < K; kb += 32) {
    __builtin_amdgcn_global_load_lds(
        (const __attribute__((address_space(1))) void*)(Ag + kb),
        (__attribute__((address_space(3))) void*)lA, 16, 0, 0);
    __builtin_amdgcn_global_load_lds(
        (const __attribute__((address_space(1))) void*)(Bg + kb),
        (__attribute__((address_space(3))) void*)lB, 16, 0, 0);
    __syncthreads();

    // A-frag layout mirrors bf16 16x16x32: lane holds A[m=lane&15][k=quad*8+j]
    long af[4], bfr[4];
#pragma unroll
    for (int r = 0; r < 4; ++r)
      af[r] = *(const long*)(AsB + (wm + r * 16 + m16) * 32 + quad * 8);
#pragma unroll
    for (int c = 0; c < 4; ++c)
      bfr[c] = *(const long*)(BsB + (wn + c * 16 + m16) * 32 + quad * 8);
#pragma unroll
    for (int r = 0; r < 4; ++r)
#pragma unroll
      for (int c = 0; c < 4; ++c)
        acc[r][c] = __builtin_amdgcn_mfma_f32_16x16x32_fp8_fp8(af[r], bfr[c],
                                                               acc[r][c], 0, 0, 0);
    __syncthreads();
  }

#pragma unroll
  for (int r = 0; r < 4; ++r) {
#pragma unroll
    for (int c = 0; c < 4; ++c) {
      const int row0 = bm + wm + r * 16 + quad * 4;
      const int col = bn + wn + c * 16 + m16;
#pragma unroll
      for (int i = 0; i < 4; ++i) {
        C[(size_t)(row0 + i) * N + col] = f2bf(acc[r][c][i] * INV_GEMM_SCALE);
      }
    }
  }
}

// ---- aggregation: relu(sum_{c in adj(node)} g[c] + b) -> fp8 (xACT_SCALE) ----
__global__ __launch_bounds__(256) void aggr_f8out(
    const unsigned short* __restrict__ g, const int* __restrict__ starts,
    const int* __restrict__ adj, const float* __restrict__ bias,
    unsigned char* __restrict__ hout) {
  const int node = blockIdx.y;
  const int f0 = blockIdx.x * 2048 + threadIdx.x * 8;
  float acc[8] = {0, 0, 0, 0, 0, 0, 0, 0};
  const int s = starts[node], e = starts[node + 1];
  int j = s;
  for (; j + 4 <= e; j += 4) {
    const int c0 = adj[j], c1 = adj[j + 1], c2 = adj[j + 2], c3 = adj[j + 3];
    u16x8 v0 = *(const u16x8*)(g + (size_t)c0 * HID_ + f0);
    u16x8 v1 = *(const u16x8*)(g + (size_t)c1 * HID_ + f0);
    u16x8 v2 = *(const u16x8*)(g + (size_t)c2 * HID_ + f0);
    u16x8 v3 = *(const u16x8*)(g + (size_t)c3 * HID_ + f0);
#pragma unroll
    for (int i = 0; i < 8; ++i)
      acc[i] += (bf2f(v0[i]) + bf2f(v1[i])) + (bf2f(v2[i]) + bf2f(v3[i]));
  }
  for (; j < e; ++j) {
    const int c = adj[j];
    u16x8 v = *(const u16x8*)(g + (size_t)c * HID_ + f0);
#pragma unroll
    for (int i = 0; i < 8; ++i) acc[i] += bf2f(v[i]);
  }
  const float4 b0 = *(const float4*)(bias + f0);
  const float4 b1 = *(const float4*)(bias + f0 + 4);
  const float bb[8] = {b0.x, b0.y, b0.z, b0.w, b1.x, b1.y, b1.z, b1.w};
  float v[8];
#pragma unroll
  for (int i = 0; i < 8; ++i) v[i] = ACT_SCALE * fmaxf(acc[i] + bb[i], 0.0f);
  int w0 = __builtin_amdgcn_cvt_pk_fp8_f32(v[0], v[1], 0, false);
  w0 = __builtin_amdgcn_cvt_pk_fp8_f32(v[2], v[3], w0, true);
  int w1 = __builtin_amdgcn_cvt_pk_fp8_f32(v[4], v[5], 0, false);
  w1 = __builtin_amdgcn_cvt_pk_fp8_f32(v[6], v[7], w1, true);
  *(int2*)(hout + (size_t)node * HID_ + f0) = make_int2(w0, w1);
}

// ---- aggregation variant emitting bf16 (final layer) ----
__global__ __launch_bounds__(256) void aggr_bf16out(
    const unsigned short* __restrict__ g, const int* __restrict__ starts,
    const int* __restrict__ adj, const float* __restrict__ bias,
    unsigned short* __restrict__ hout) {
  const int node = blockIdx.y;
  const int f0 = blockIdx.x * 2048 + threadIdx.x * 8;
  float acc[8] = {0, 0, 0, 0, 0, 0, 0, 0};
  const int s = starts[node], e = starts[node + 1];
  int j = s;
  for (; j + 4 <= e; j += 4) {
    const int c0 = adj[j], c1 = adj[j + 1], c2 = adj[j + 2], c3 = adj[j + 3];
    u16x8 v0 = *(const u16x8*)(g + (size_t)c0 * HID_ + f0);
    u16x8 v1 = *(const u16x8*)(g + (size_t)c1 * HID_ + f0);
    u16x8 v2 = *(const u16x8*)(g + (size_t)c2 * HID_ + f0);
    u16x8 v3 = *(const u16x8*)(g + (size_t)c3 * HID_ + f0);
#pragma unroll
    for (int i = 0; i < 8; ++i)
      acc[i] += (bf2f(v0[i]) + bf2f(v1[i])) + (bf2f(v2[i]) + bf2f(v3[i]));
  }
  for (; j < e; ++j) {
    const int c = adj[j];
    u16x8 v = *(const u16x8*)(g + (size_t)c * HID_ + f0);
#pragma unroll
    for (int i = 0; i < 8; ++i) acc[i] += bf2f(v[i]);
  }
  const float4 b0 = *(const float4*)(bias + f0);
  const float4 b1 = *(const float4*)(bias + f0 + 4);
  const float bb[8] = {b0.x, b0.y, b0.z, b0.w, b1.x, b1.y, b1.z, b1.w};
  u16x8 r;
#pragma unroll
  for (int i = 0; i < 8; ++i) r[i] = f2bf(fmaxf(acc[i] + bb[i], 0.0f));
  *(u16x8*)(hout + (size_t)node * HID_ + f0) = r;
}

// ---------------- hm[row] = mean(h[row,:]) ----------------
__global__ __launch_bounds__(256) void row_mean(const unsigned short* __restrict__ h,
                                                float* __restrict__ hm) {
  const int row = blockIdx.x, t = threadIdx.x;
  const u16x8* p = (const u16x8*)(h + (size_t)row * HID_);
  u16x8 v1 = p[t], v2 = p[t + 256];
  float s = 0.f;
#pragma unroll
  for (int i = 0; i < 8; ++i) s += bf2f(v1[i]) + bf2f(v2[i]);
  for (int off = 32; off > 0; off >>= 1) s += __shfl_down(s, off);
  __shared__ float ws[4];
  if ((t & 63) == 0) ws[t >> 6] = s;
  __syncthreads();
  if (t == 0) hm[row] = (ws[0] + ws[1] + ws[2] + ws[3]) * (1.0f / (float)HID_);
}

// ---------------- z[j] = relu(Wc1[j,:].hm + bc1[j]), one wave per j ----------------
__global__ __launch_bounds__(256) void clf1(const float* __restrict__ Wc1,
                                            const float* __restrict__ bc1,
                                            const float* __restrict__ hm,
                                            float* __restrict__ z) {
  const int wave = threadIdx.x >> 6, lane = threadIdx.x & 63;
  const int j = blockIdx.x * 4 + wave;
  const float* w = Wc1 + (size_t)j * HID_;
  float s = 0.f;
  for (int i = lane; i < HID_; i += 64) s += w[i] * hm[i];
  for (int off = 32; off > 0; off >>= 1) s += __shfl_down(s, off);
  if (lane == 0) z[j] = fmaxf(s + bc1[j], 0.0f);
}

// ---------------- out = Wc2.z + bc2 ----------------
__global__ __launch_bounds__(256) void clf2(const float* __restrict__ Wc2,
                                            const float* __restrict__ bc2,
                                            const float* __restrict__ z,
                                            float* __restrict__ out) {
  const int t = threadIdx.x;
  float s = 0.f;
  for (int i = t; i < HID_ / 2; i += 256) s += z[i] * Wc2[i];
  for (int off = 32; off > 0; off >>= 1) s += __shfl_down(s, off);
  __shared__ float ws[4];
  if ((t & 63) == 0) ws[t >> 6] = s;
  __syncthreads();
  if (t == 0) out[0] = ws[0] + ws[1] + ws[2] + ws[3] + bc2[0];
}

extern "C" void kernel_launch(void* const* d_in, const int* in_sizes, int n_in,
                              void* d_out, int out_size, void* d_ws, size_t ws_size,
                              hipStream_t stream) {
  (void)in_sizes; (void)n_in; (void)out_size; (void)ws_size;
  const float* x       = (const float*)d_in[0];
  const int*   edge    = (const int*)d_in[1];
  const int*   row     = edge;
  const int*   col     = edge + NEDGE;
  const float* W_embed = (const float*)d_in[2];
  const float* b_embed = (const float*)d_in[3];
  const float* W1      = (const float*)d_in[4];
  const float* b1      = (const float*)d_in[5];
  const float* W2      = (const float*)d_in[6];
  const float* b2      = (const float*)d_in[7];
  const float* Wc1     = (const float*)d_in[8];
  const float* bc1     = (const float*)d_in[9];
  const float* Wc2     = (const float*)d_in[10];
  const float* bc2     = (const float*)d_in[11];
  float* out = (float*)d_out;

  char* ws = (char*)d_ws;
  size_t off = 0;
  auto alloc = [&](size_t bytes) {
    char* p = ws + off;
    off += (bytes + 255) & ~(size_t)255;
    return p;
  };
  unsigned short* xb   = (unsigned short*)alloc((size_t)N_NODES * IN_DIM_ * 2);
  unsigned short* web  = (unsigned short*)alloc((size_t)HID_ * IN_DIM_ * 2);
  unsigned char*  w1f8 = (unsigned char*)alloc((size_t)HID_ * HID_);
  unsigned char*  w2f8 = (unsigned char*)alloc((size_t)HID_ * HID_);
  unsigned char*  h0f8 = (unsigned char*)alloc((size_t)N_NODES * HID_);
  unsigned char*  h1f8 = (unsigned char*)alloc((size_t)N_NODES * HID_);
  unsigned short* g    = (unsigned short*)alloc((size_t)N_NODES * HID_ * 2);
  unsigned short* h2   = (unsigned short*)alloc((size_t)N_NODES * HID_ * 2);
  int* counts = (int*)alloc(N_NODES * 4);
  int* cursor = (int*)alloc(N_NODES * 4);
  int* starts = (int*)alloc((N_NODES + 1) * 4);
  int* adj    = (int*)alloc(NEDGE * 4);
  float* hm   = (float*)alloc(N_NODES * 4);
  float* z    = (float*)alloc((HID_ / 2) * 4);

  // CSR build (ws is re-poisoned each call -> must zero)
  zero_i32<<<16, 256, 0, stream>>>(counts, N_NODES);
  zero_i32<<<16, 256, 0, stream>>>(cursor, N_NODES);
  hist_rows<<<NEDGE / 256, 256, 0, stream>>>(row, counts);
  scan4096<<<1, 1024, 0, stream>>>(counts, starts);
  fill_adj<<<NEDGE / 256, 256, 0, stream>>>(row, col, starts, cursor, adj);

  // dtype conversions
  cvt_bf16<<<(N_NODES * IN_DIM_ / 8) / 256, 256, 0, stream>>>(x, xb, N_NODES * IN_DIM_);
  cvt_bf16<<<(HID_ * IN_DIM_ / 8) / 256, 256, 0, stream>>>(W_embed, web, HID_ * IN_DIM_);
  cvt_fp8<<<(HID_ * HID_ / 8) / 256, 256, 0, stream>>>(W1, w1f8, HID_ * HID_, W_SCALE);
  cvt_fp8<<<(HID_ * HID_ / 8) / 256, 256, 0, stream>>>(W2, w2f8, HID_ * HID_, W_SCALE);

  // embed (bf16): h0f8 = fp8(8 * (x @ We^T + be))
  gemm_bt_f8out<<<dim3(32, 32), 256, 0, stream>>>(xb, web, h0f8, N_NODES, HID_,
                                                  IN_DIM_, b_embed);
  // layer 1: g = (h0 @ W1^T) ; h1f8 = fp8(8 * relu(A g + b1))
  gemm_fp8<<<dim3(32, 32), 256, 0, stream>>>(h0f8, w1f8, g, N_NODES, HID_, HID_);
  aggr_f8out<<<dim3(2, N_NODES), 256, 0, stream>>>(g, starts, adj, b1, h1f8);
  // layer 2: g = (h1 @ W2^T) ; h2 = relu(A g + b2)  (bf16)
  gemm_fp8<<<dim3(32, 32), 256, 0, stream>>>(h1f8, w2f8, g, N_NODES, HID_, HID_);
  aggr_bf16out<<<dim3(2, N_NODES), 256, 0, stream>>>(g, starts, adj, b2, h2);
  // classifier tail
  row_mean<<<N_NODES, 256, 0, stream>>>(h2, hm);
  clf1<<<(HID_ / 2) / 4, 256, 0, stream>>>(Wc1, bc1, hm, z);
  clf2<<<1, 256, 0, stream>>>(Wc2, bc2, z, out);
}

// Round 5
// 563.795 us; speedup vs baseline: 1.4510x; 1.4001x over previous
//
#include <hip/hip_runtime.h>
#include <hip/hip_bf16.h>

// GNN: h = x@We^T + be; 2x { h = relu(segsum(h[col],row) @ W^T + b) };
// out = relu(mean(h,1) @ Wc1^T + bc1) @ Wc2^T + bc2   (scalar fp32)
//
// Restructure: relu((A h) W^T + b) == relu(A (h W^T) + b)  (A = sparse adj).
// R5 (= R4 + compile fix): fp8 GEMM with BK=64 and a GLOBAL k-column
// permutation (shared by A and B, so A@B^T invariant) chosen so each lane's
// single ds_read_b128 at row*64 + quad*16 (the empirically conflict-cheap R1
// pattern) yields both k-step fragments. g stored fp8 (scale 8): halves
// epilogue writes + aggr gather bytes. Feature-dim buffers live in permuted
// order end-to-end; biases via inverse perm. fp8->f32 decode via packed
// __builtin_amdgcn_cvt_pk_f32_fp8 (literal word-select; scalar form requires
// frontend-constant byte index -> R4 compile failure).

#define N_NODES 4096
#define IN_DIM_ 512
#define HID_ 4096
#define NEDGE 65536

typedef __bf16 bf16x8 __attribute__((ext_vector_type(8)));
typedef float f32x4 __attribute__((ext_vector_type(4)));
typedef float f32x2 __attribute__((ext_vector_type(2)));
typedef unsigned short u16x8 __attribute__((ext_vector_type(8)));
typedef long lx2 __attribute__((ext_vector_type(2)));

#define ACT_SCALE 8.0f     // h fp8 = 8 x true
#define W_SCALE 256.0f     // W fp8 = 256 x true
#define G_SCALE 8.0f       // g fp8 = 8 x true
// gemm acc = 2048 x true; g store multiplier = 8/2048
#define G_STORE_MUL (8.0f / 2048.0f)

// k-permutation within each 64-group, in 8-elem chunks:
// orig chunk g -> permuted chunk p = (g<4) ? 2g : 2(g-4)+1
__device__ __forceinline__ int fwd_chunk(int g) {
  return (g < 4) ? (2 * g) : (2 * (g - 4) + 1);
}
// inverse: p -> g = (p>>1) + (p&1)*4
__device__ __forceinline__ int inv_chunk(int p) {
  return (p >> 1) + (p & 1) * 4;
}
// permute a full element index (feature dim)
__device__ __forceinline__ int perm_col(int k) {
  return (k & ~63) + fwd_chunk((k >> 3) & 7) * 8 + (k & 7);
}

__device__ __forceinline__ unsigned short f2bf(float f) {
  unsigned u = __float_as_uint(f);
  return (unsigned short)((u + 0x7fffu + ((u >> 16) & 1u)) >> 16);  // RNE
}
__device__ __forceinline__ float bf2f(unsigned short h) {
  return __uint_as_float((unsigned)h << 16);
}
__device__ __forceinline__ unsigned char f2fp8(float f) {
  int w = __builtin_amdgcn_cvt_pk_fp8_f32(f, f, 0, false);  // OCP e4m3
  return (unsigned char)(w & 0xff);
}
// decode 4 fp8 bytes of w into acc[0..3] (+=)
__device__ __forceinline__ void fp8x4_acc(int w, float* acc) {
  f32x2 lo = __builtin_amdgcn_cvt_pk_f32_fp8(w, false);
  f32x2 hi = __builtin_amdgcn_cvt_pk_f32_fp8(w, true);
  acc[0] += lo[0]; acc[1] += lo[1]; acc[2] += hi[0]; acc[3] += hi[1];
}

// ---------------- fp32 -> bf16, 8 elems/thread ----------------
__global__ __launch_bounds__(256) void cvt_bf16(const float* __restrict__ in,
                                                unsigned short* __restrict__ out,
                                                int n) {
  int i = (blockIdx.x * 256 + threadIdx.x) * 8;
  if (i >= n) return;
  const float4 a = *(const float4*)(in + i);
  const float4 b = *(const float4*)(in + i + 4);
  u16x8 r;
  r[0] = f2bf(a.x); r[1] = f2bf(a.y); r[2] = f2bf(a.z); r[3] = f2bf(a.w);
  r[4] = f2bf(b.x); r[5] = f2bf(b.y); r[6] = f2bf(b.z); r[7] = f2bf(b.w);
  *(u16x8*)(out + i) = r;
}

// ---- fp32 -> fp8 e4m3 (x scale), 8 elems/thread, k-permuted destination ----
// flat index; rows have length K (mult of 64) so 64-groups never cross rows.
__global__ __launch_bounds__(256) void cvt_fp8_perm(const float* __restrict__ in,
                                                    unsigned char* __restrict__ out,
                                                    int n, float scale) {
  int i = (blockIdx.x * 256 + threadIdx.x) * 8;  // orig index, 8-aligned chunk
  if (i >= n) return;
  const float4 a = *(const float4*)(in + i);
  const float4 b = *(const float4*)(in + i + 4);
  int w0 = __builtin_amdgcn_cvt_pk_fp8_f32(a.x * scale, a.y * scale, 0, false);
  w0 = __builtin_amdgcn_cvt_pk_fp8_f32(a.z * scale, a.w * scale, w0, true);
  int w1 = __builtin_amdgcn_cvt_pk_fp8_f32(b.x * scale, b.y * scale, 0, false);
  w1 = __builtin_amdgcn_cvt_pk_fp8_f32(b.z * scale, b.w * scale, w1, true);
  const int dest = (i & ~63) + fwd_chunk((i >> 3) & 7) * 8;
  *(int2*)(out + dest) = make_int2(w0, w1);
}

// ---------------- CSR build ----------------
__global__ __launch_bounds__(256) void zero_i32(int* __restrict__ p, int n) {
  int i = blockIdx.x * 256 + threadIdx.x;
  if (i < n) p[i] = 0;
}

__global__ __launch_bounds__(256) void hist_rows(const int* __restrict__ row,
                                                 int* __restrict__ counts) {
  int e = blockIdx.x * 256 + threadIdx.x;
  if (e < NEDGE) atomicAdd(&counts[row[e]], 1);
}

// exclusive scan of counts[4096] -> starts[4097]; single block of 1024 threads
__global__ __launch_bounds__(1024) void scan4096(const int* __restrict__ counts,
                                                 int* __restrict__ starts) {
  __shared__ int sa[1024], sb[1024];
  const int t = threadIdx.x;
  const int c0 = counts[t * 4], c1 = counts[t * 4 + 1],
            c2 = counts[t * 4 + 2], c3 = counts[t * 4 + 3];
  const int local = c0 + c1 + c2 + c3;
  sa[t] = local;
  __syncthreads();
  int* src = sa; int* dst = sb;
  for (int off = 1; off < 1024; off <<= 1) {
    int v = src[t];
    if (t >= off) v += src[t - off];
    dst[t] = v;
    __syncthreads();
    int* tmp = src; src = dst; dst = tmp;
  }
  const int excl = (t == 0) ? 0 : src[t - 1];
  starts[t * 4]     = excl;
  starts[t * 4 + 1] = excl + c0;
  starts[t * 4 + 2] = excl + c0 + c1;
  starts[t * 4 + 3] = excl + c0 + c1 + c2;
  if (t == 1023) starts[4096] = excl + local;
}

__global__ __launch_bounds__(256) void fill_adj(const int* __restrict__ row,
                                                const int* __restrict__ col,
                                                const int* __restrict__ starts,
                                                int* __restrict__ cursor,
                                                int* __restrict__ adj) {
  int e = blockIdx.x * 256 + threadIdx.x;
  if (e >= NEDGE) return;
  int r = row[e];
  int p = atomicAdd(&cursor[r], 1);
  adj[starts[r] + p] = col[e];
}

// ------- bf16 GEMM (embed): h0 = fp8(ACT_SCALE*(A@B^T + bias)), permuted cols
__global__ __launch_bounds__(256) void gemm_bt_f8out(
    const unsigned short* __restrict__ A, const unsigned short* __restrict__ B,
    unsigned char* __restrict__ C, int M, int N, int K,
    const float* __restrict__ bias) {
  __shared__ unsigned short As[128 * 32];
  __shared__ unsigned short Bs[128 * 32];
  const int t = threadIdx.x;
  const int bm = blockIdx.x * 128, bn = blockIdx.y * 128;
  const int wave = t >> 6, lane = t & 63;
  const int wm = (wave >> 1) * 64, wn = (wave & 1) * 64;
  const int m16 = lane & 15, quad = lane >> 4;

  f32x4 acc[4][4] = {};

  const int srow = t >> 2;
  const int scol = (t & 3) * 8;
  const unsigned short* Ag0 = A + (size_t)(bm + srow) * K + scol;
  const unsigned short* Ag1 = A + (size_t)(bm + 64 + srow) * K + scol;
  const unsigned short* Bg0 = B + (size_t)(bn + srow) * K + scol;
  const unsigned short* Bg1 = B + (size_t)(bn + 64 + srow) * K + scol;
  char* AsB = (char*)As;
  char* BsB = (char*)Bs;
  char* lA0 = AsB + t * 16;
  char* lA1 = AsB + 4096 + t * 16;
  char* lB0 = BsB + t * 16;
  char* lB1 = BsB + 4096 + t * 16;

  for (int kb = 0; kb < K; kb += 32) {
    __builtin_amdgcn_global_load_lds(
        (const __attribute__((address_space(1))) void*)(Ag0 + kb),
        (__attribute__((address_space(3))) void*)lA0, 16, 0, 0);
    __builtin_amdgcn_global_load_lds(
        (const __attribute__((address_space(1))) void*)(Ag1 + kb),
        (__attribute__((address_space(3))) void*)lA1, 16, 0, 0);
    __builtin_amdgcn_global_load_lds(
        (const __attribute__((address_space(1))) void*)(Bg0 + kb),
        (__attribute__((address_space(3))) void*)lB0, 16, 0, 0);
    __builtin_amdgcn_global_load_lds(
        (const __attribute__((address_space(1))) void*)(Bg1 + kb),
        (__attribute__((address_space(3))) void*)lB1, 16, 0, 0);
    __syncthreads();

    bf16x8 af[4], bfr[4];
#pragma unroll
    for (int r = 0; r < 4; ++r)
      af[r] = *(const bf16x8*)(AsB + (wm + r * 16 + m16) * 64 + quad * 16);
#pragma unroll
    for (int c = 0; c < 4; ++c)
      bfr[c] = *(const bf16x8*)(BsB + (wn + c * 16 + m16) * 64 + quad * 16);
#pragma unroll
    for (int r = 0; r < 4; ++r)
#pragma unroll
      for (int c = 0; c < 4; ++c)
        acc[r][c] = __builtin_amdgcn_mfma_f32_16x16x32_bf16(af[r], bfr[c],
                                                            acc[r][c], 0, 0, 0);
    __syncthreads();
  }

  // C/D layout (m89/m91): col = lane&15, row = quad*4 + reg
#pragma unroll
  for (int r = 0; r < 4; ++r) {
#pragma unroll
    for (int c = 0; c < 4; ++c) {
      const int row0 = bm + wm + r * 16 + quad * 4;
      const int col = bn + wn + c * 16 + m16;
      const int cp = perm_col(col);
      const float bv = bias[col];
#pragma unroll
      for (int i = 0; i < 4; ++i) {
        float v = acc[r][c][i] + bv;
        C[(size_t)(row0 + i) * N + cp] = f2fp8(ACT_SCALE * v);
      }
    }
  }
}

// ------- fp8 GEMM (k-permuted operands): g = fp8(G_STORE_MUL*acc), perm cols
// BK=64; LDS row = 64 B; single ds_read_b128 per fragment-pair at the
// empirically conflict-cheap pattern row*64 + quad*16. 32 MFMA / barrier.
__global__ __launch_bounds__(256) void gemm_fp8p(
    const unsigned char* __restrict__ A, const unsigned char* __restrict__ B,
    unsigned char* __restrict__ C, int M, int N, int K) {
  __shared__ unsigned char As[128 * 64];  // 8 KB
  __shared__ unsigned char Bs[128 * 64];  // 8 KB
  const int t = threadIdx.x;
  const int bm = blockIdx.x * 128, bn = blockIdx.y * 128;
  const int wave = t >> 6, lane = t & 63;
  const int wm = (wave >> 1) * 64, wn = (wave & 1) * 64;
  const int m16 = lane & 15, quad = lane >> 4;

  f32x4 acc[4][4] = {};

  // staging: thread t -> row t>>2 (0..63), 16B chunk t&3
  const int srow = t >> 2;
  const int scol = (t & 3) * 16;
  const unsigned char* Ag0 = A + (size_t)(bm + srow) * K + scol;
  const unsigned char* Ag1 = A + (size_t)(bm + 64 + srow) * K + scol;
  const unsigned char* Bg0 = B + (size_t)(bn + srow) * K + scol;
  const unsigned char* Bg1 = B + (size_t)(bn + 64 + srow) * K + scol;
  char* AsB = (char*)As;
  char* BsB = (char*)Bs;
  char* lA0 = AsB + t * 16;
  char* lA1 = AsB + 4096 + t * 16;
  char* lB0 = BsB + t * 16;
  char* lB1 = BsB + 4096 + t * 16;

  for (int kb = 0; kb < K; kb += 64) {
    __builtin_amdgcn_global_load_lds(
        (const __attribute__((address_space(1))) void*)(Ag0 + kb),
        (__attribute__((address_space(3))) void*)lA0, 16, 0, 0);
    __builtin_amdgcn_global_load_lds(
        (const __attribute__((address_space(1))) void*)(Ag1 + kb),
        (__attribute__((address_space(3))) void*)lA1, 16, 0, 0);
    __builtin_amdgcn_global_load_lds(
        (const __attribute__((address_space(1))) void*)(Bg0 + kb),
        (__attribute__((address_space(3))) void*)lB0, 16, 0, 0);
    __builtin_amdgcn_global_load_lds(
        (const __attribute__((address_space(1))) void*)(Bg1 + kb),
        (__attribute__((address_space(3))) void*)lB1, 16, 0, 0);
    __syncthreads();

    // one b128 per fragment-pair: [0]=k-sub0 (orig k quad*8..+8),
    // [1]=k-sub1 (orig k 32+quad*8..+8) -- by construction of the k-perm.
    lx2 af[4], bfr[4];
#pragma unroll
    for (int r = 0; r < 4; ++r)
      af[r] = *(const lx2*)(AsB + (wm + r * 16 + m16) * 64 + quad * 16);
#pragma unroll
    for (int c = 0; c < 4; ++c)
      bfr[c] = *(const lx2*)(BsB + (wn + c * 16 + m16) * 64 + quad * 16);
#pragma unroll
    for (int ks = 0; ks < 2; ++ks)
#pragma unroll
      for (int r = 0; r < 4; ++r)
#pragma unroll
        for (int c = 0; c < 4; ++c)
          acc[r][c] = __builtin_amdgcn_mfma_f32_16x16x32_fp8_fp8(
              af[r][ks], bfr[c][ks], acc[r][c], 0, 0, 0);
    __syncthreads();
  }

#pragma unroll
  for (int r = 0; r < 4; ++r) {
#pragma unroll
    for (int c = 0; c < 4; ++c) {
      const int row0 = bm + wm + r * 16 + quad * 4;
      const int col = bn + wn + c * 16 + m16;
      const int cp = perm_col(col);
#pragma unroll
      for (int i = 0; i < 4; ++i) {
        C[(size_t)(row0 + i) * N + cp] = f2fp8(acc[r][c][i] * G_STORE_MUL);
      }
    }
  }
}

// ---- aggregation (fp8 g in): h = relu(sum g[c]/G_SCALE + b) -> fp8 x ACT ----
// feature dim stays in permuted order; bias fetched via inverse perm.
__global__ __launch_bounds__(256) void aggr_f8out(
    const unsigned char* __restrict__ g, const int* __restrict__ starts,
    const int* __restrict__ adj, const float* __restrict__ bias,
    unsigned char* __restrict__ hout) {
  const int node = blockIdx.y;
  const int f0 = blockIdx.x * 2048 + threadIdx.x * 8;  // permuted position
  float acc[8] = {0, 0, 0, 0, 0, 0, 0, 0};
  const int s = starts[node], e = starts[node + 1];
  int j = s;
  for (; j + 4 <= e; j += 4) {
    const int c0 = adj[j], c1 = adj[j + 1], c2 = adj[j + 2], c3 = adj[j + 3];
    int2 v0 = *(const int2*)(g + (size_t)c0 * HID_ + f0);
    int2 v1 = *(const int2*)(g + (size_t)c1 * HID_ + f0);
    int2 v2 = *(const int2*)(g + (size_t)c2 * HID_ + f0);
    int2 v3 = *(const int2*)(g + (size_t)c3 * HID_ + f0);
    fp8x4_acc(v0.x, acc);     fp8x4_acc(v0.y, acc + 4);
    fp8x4_acc(v1.x, acc);     fp8x4_acc(v1.y, acc + 4);
    fp8x4_acc(v2.x, acc);     fp8x4_acc(v2.y, acc + 4);
    fp8x4_acc(v3.x, acc);     fp8x4_acc(v3.y, acc + 4);
  }
  for (; j < e; ++j) {
    int2 v = *(const int2*)(g + (size_t)adj[j] * HID_ + f0);
    fp8x4_acc(v.x, acc);      fp8x4_acc(v.y, acc + 4);
  }
  // bias: orig chunk for this permuted 8-chunk
  const int orig0 = (f0 & ~63) + inv_chunk((f0 >> 3) & 7) * 8;
  const float4 b0 = *(const float4*)(bias + orig0);
  const float4 b1 = *(const float4*)(bias + orig0 + 4);
  const float bb[8] = {b0.x, b0.y, b0.z, b0.w, b1.x, b1.y, b1.z, b1.w};
  float v[8];
#pragma unroll
  for (int i = 0; i < 8; ++i)
    v[i] = ACT_SCALE * fmaxf(acc[i] * (1.0f / G_SCALE) + bb[i], 0.0f);
  int w0 = __builtin_amdgcn_cvt_pk_fp8_f32(v[0], v[1], 0, false);
  w0 = __builtin_amdgcn_cvt_pk_fp8_f32(v[2], v[3], w0, true);
  int w1 = __builtin_amdgcn_cvt_pk_fp8_f32(v[4], v[5], 0, false);
  w1 = __builtin_amdgcn_cvt_pk_fp8_f32(v[6], v[7], w1, true);
  *(int2*)(hout + (size_t)node * HID_ + f0) = make_int2(w0, w1);
}

// ---- aggregation variant emitting bf16 (final layer; still permuted) ----
__global__ __launch_bounds__(256) void aggr_bf16out(
    const unsigned char* __restrict__ g, const int* __restrict__ starts,
    const int* __restrict__ adj, const float* __restrict__ bias,
    unsigned short* __restrict__ hout) {
  const int node = blockIdx.y;
  const int f0 = blockIdx.x * 2048 + threadIdx.x * 8;
  float acc[8] = {0, 0, 0, 0, 0, 0, 0, 0};
  const int s = starts[node], e = starts[node + 1];
  int j = s;
  for (; j + 4 <= e; j += 4) {
    const int c0 = adj[j], c1 = adj[j + 1], c2 = adj[j + 2], c3 = adj[j + 3];
    int2 v0 = *(const int2*)(g + (size_t)c0 * HID_ + f0);
    int2 v1 = *(const int2*)(g + (size_t)c1 * HID_ + f0);
    int2 v2 = *(const int2*)(g + (size_t)c2 * HID_ + f0);
    int2 v3 = *(const int2*)(g + (size_t)c3 * HID_ + f0);
    fp8x4_acc(v0.x, acc);     fp8x4_acc(v0.y, acc + 4);
    fp8x4_acc(v1.x, acc);     fp8x4_acc(v1.y, acc + 4);
    fp8x4_acc(v2.x, acc);     fp8x4_acc(v2.y, acc + 4);
    fp8x4_acc(v3.x, acc);     fp8x4_acc(v3.y, acc + 4);
  }
  for (; j < e; ++j) {
    int2 v = *(const int2*)(g + (size_t)adj[j] * HID_ + f0);
    fp8x4_acc(v.x, acc);      fp8x4_acc(v.y, acc + 4);
  }
  const int orig0 = (f0 & ~63) + inv_chunk((f0 >> 3) & 7) * 8;
  const float4 b0 = *(const float4*)(bias + orig0);
  const float4 b1 = *(const float4*)(bias + orig0 + 4);
  const float bb[8] = {b0.x, b0.y, b0.z, b0.w, b1.x, b1.y, b1.z, b1.w};
  u16x8 r;
#pragma unroll
  for (int i = 0; i < 8; ++i)
    r[i] = f2bf(fmaxf(acc[i] * (1.0f / G_SCALE) + bb[i], 0.0f));
  *(u16x8*)(hout + (size_t)node * HID_ + f0) = r;
}

// ---------------- hm[row] = mean(h[row,:])  (perm-invariant) ----------------
__global__ __launch_bounds__(256) void row_mean(const unsigned short* __restrict__ h,
                                                float* __restrict__ hm) {
  const int row = blockIdx.x, t = threadIdx.x;
  const u16x8* p = (const u16x8*)(h + (size_t)row * HID_);
  u16x8 v1 = p[t], v2 = p[t + 256];
  float s = 0.f;
#pragma unroll
  for (int i = 0; i < 8; ++i) s += bf2f(v1[i]) + bf2f(v2[i]);
  for (int off = 32; off > 0; off >>= 1) s += __shfl_down(s, off);
  __shared__ float ws[4];
  if ((t & 63) == 0) ws[t >> 6] = s;
  __syncthreads();
  if (t == 0) hm[row] = (ws[0] + ws[1] + ws[2] + ws[3]) * (1.0f / (float)HID_);
}

// ---------------- z[j] = relu(Wc1[j,:].hm + bc1[j]), one wave per j ----------------
__global__ __launch_bounds__(256) void clf1(const float* __restrict__ Wc1,
                                            const float* __restrict__ bc1,
                                            const float* __restrict__ hm,
                                            float* __restrict__ z) {
  const int wave = threadIdx.x >> 6, lane = threadIdx.x & 63;
  const int j = blockIdx.x * 4 + wave;
  const float* w = Wc1 + (size_t)j * HID_;
  float s = 0.f;
  for (int i = lane; i < HID_; i += 64) s += w[i] * hm[i];
  for (int off = 32; off > 0; off >>= 1) s += __shfl_down(s, off);
  if (lane == 0) z[j] = fmaxf(s + bc1[j], 0.0f);
}

// ---------------- out = Wc2.z + bc2 ----------------
__global__ __launch_bounds__(256) void clf2(const float* __restrict__ Wc2,
                                            const float* __restrict__ bc2,
                                            const float* __restrict__ z,
                                            float* __restrict__ out) {
  const int t = threadIdx.x;
  float s = 0.f;
  for (int i = t; i < HID_ / 2; i += 256) s += z[i] * Wc2[i];
  for (int off = 32; off > 0; off >>= 1) s += __shfl_down(s, off);
  __shared__ float ws[4];
  if ((t & 63) == 0) ws[t >> 6] = s;
  __syncthreads();
  if (t == 0) out[0] = ws[0] + ws[1] + ws[2] + ws[3] + bc2[0];
}

extern "C" void kernel_launch(void* const* d_in, const int* in_sizes, int n_in,
                              void* d_out, int out_size, void* d_ws, size_t ws_size,
                              hipStream_t stream) {
  (void)in_sizes; (void)n_in; (void)out_size; (void)ws_size;
  const float* x       = (const float*)d_in[0];
  const int*   edge    = (const int*)d_in[1];
  const int*   row     = edge;
  const int*   col     = edge + NEDGE;
  const float* W_embed = (const float*)d_in[2];
  const float* b_embed = (const float*)d_in[3];
  const float* W1      = (const float*)d_in[4];
  const float* b1      = (const float*)d_in[5];
  const float* W2      = (const float*)d_in[6];
  const float* b2      = (const float*)d_in[7];
  const float* Wc1     = (const float*)d_in[8];
  const float* bc1     = (const float*)d_in[9];
  const float* Wc2     = (const float*)d_in[10];
  const float* bc2     = (const float*)d_in[11];
  float* out = (float*)d_out;

  char* ws = (char*)d_ws;
  size_t off = 0;
  auto alloc = [&](size_t bytes) {
    char* p = ws + off;
    off += (bytes + 255) & ~(size_t)255;
    return p;
  };
  unsigned short* xb   = (unsigned short*)alloc((size_t)N_NODES * IN_DIM_ * 2);
  unsigned short* web  = (unsigned short*)alloc((size_t)HID_ * IN_DIM_ * 2);
  unsigned char*  w1f8 = (unsigned char*)alloc((size_t)HID_ * HID_);
  unsigned char*  w2f8 = (unsigned char*)alloc((size_t)HID_ * HID_);
  unsigned char*  h0f8 = (unsigned char*)alloc((size_t)N_NODES * HID_);
  unsigned char*  h1f8 = (unsigned char*)alloc((size_t)N_NODES * HID_);
  unsigned char*  g    = (unsigned char*)alloc((size_t)N_NODES * HID_);
  unsigned short* h2   = (unsigned short*)alloc((size_t)N_NODES * HID_ * 2);
  int* counts = (int*)alloc(N_NODES * 4);
  int* cursor = (int*)alloc(N_NODES * 4);
  int* starts = (int*)alloc((N_NODES + 1) * 4);
  int* adj    = (int*)alloc(NEDGE * 4);
  float* hm   = (float*)alloc(N_NODES * 4);
  float* z    = (float*)alloc((HID_ / 2) * 4);

  // CSR build (ws is re-poisoned each call -> must zero)
  zero_i32<<<16, 256, 0, stream>>>(counts, N_NODES);
  zero_i32<<<16, 256, 0, stream>>>(cursor, N_NODES);
  hist_rows<<<NEDGE / 256, 256, 0, stream>>>(row, counts);
  scan4096<<<1, 1024, 0, stream>>>(counts, starts);
  fill_adj<<<NEDGE / 256, 256, 0, stream>>>(row, col, starts, cursor, adj);

  // dtype conversions (weights: k-permuted fp8)
  cvt_bf16<<<(N_NODES * IN_DIM_ / 8) / 256, 256, 0, stream>>>(x, xb, N_NODES * IN_DIM_);
  cvt_bf16<<<(HID_ * IN_DIM_ / 8) / 256, 256, 0, stream>>>(W_embed, web, HID_ * IN_DIM_);
  cvt_fp8_perm<<<(HID_ * HID_ / 8) / 256, 256, 0, stream>>>(W1, w1f8, HID_ * HID_, W_SCALE);
  cvt_fp8_perm<<<(HID_ * HID_ / 8) / 256, 256, 0, stream>>>(W2, w2f8, HID_ * HID_, W_SCALE);

  // embed (bf16): h0 = fp8(8 * (x @ We^T + be)), permuted feature order
  gemm_bt_f8out<<<dim3(32, 32), 256, 0, stream>>>(xb, web, h0f8, N_NODES, HID_,
                                                  IN_DIM_, b_embed);
  // layer 1: g = h0 @ W1^T (fp8, perm); h1 = fp8(8 * relu(A g + b1))
  gemm_fp8p<<<dim3(32, 32), 256, 0, stream>>>(h0f8, w1f8, g, N_NODES, HID_, HID_);
  aggr_f8out<<<dim3(2, N_NODES), 256, 0, stream>>>(g, starts, adj, b1, h1f8);
  // layer 2: g = h1 @ W2^T ; h2 = relu(A g + b2) (bf16, perm)
  gemm_fp8p<<<dim3(32, 32), 256, 0, stream>>>(h1f8, w2f8, g, N_NODES, HID_, HID_);
  aggr_bf16out<<<dim3(2, N_NODES), 256, 0, stream>>>(g, starts, adj, b2, h2);
  // classifier tail (row_mean is perm-invariant)
  row_mean<<<N_NODES, 256, 0, stream>>>(h2, hm);
  clf1<<<(HID_ / 2) / 4, 256, 0, stream>>>(Wc1, bc1, hm, z);
  clf2<<<1, 256, 0, stream>>>(Wc2, bc2, z, out);
}

// Round 6
// 483.253 us; speedup vs baseline: 1.6929x; 1.1667x over previous
//
#include <hip/hip_runtime.h>
#include <hip/hip_bf16.h>

// GNN: h = x@We^T + be; 2x { h = relu(segsum(h[col],row) @ W^T + b) };
// out = relu(mean(h,1) @ Wc1^T + bc1) @ Wc2^T + bc2   (scalar fp32)
//
// Restructure: relu((A h) W^T + b) == relu(A (h W^T) + b)  (A = sparse adj).
// R6: all three GEMMs via MX-scaled fp8 mfma_scale_f32_16x16x128_f8f6f4
// (2x plain-fp8 rate; unit E8M0 scales 0x7F = numerics of plain fp8).
// BK=128. LDS tile granule-split into two 64-B-stride blocks (As0: orig 16-B
// granule 2q at position q; As1: granule 2q+1) so each lane's 32-B fragment
// is two ds_read_b128 at the empirically conflict-cheap pattern
// row*64 + quad*16. The granule shuffle is folded into the per-lane GLOBAL
// addresses of global_load_lds (LDS side stays uniform+t*16) -- no permuted
// buffers anywhere; everything is in natural order.

#define N_NODES 4096
#define IN_DIM_ 512
#define HID_ 4096
#define NEDGE 65536

typedef float f32x4 __attribute__((ext_vector_type(4)));
typedef float f32x2 __attribute__((ext_vector_type(2)));
typedef unsigned short u16x8 __attribute__((ext_vector_type(8)));
typedef int i32x8 __attribute__((ext_vector_type(8)));

#define ACT_SCALE 8.0f     // activations fp8 = 8 x true
#define W_SCALE 256.0f     // weights fp8 = 256 x true
#define G_SCALE 8.0f       // g fp8 = 8 x true
// gemm acc = 2048 x true; fp8-store multiplier = 8/2048
#define G_STORE_MUL (8.0f / 2048.0f)

__device__ __forceinline__ unsigned short f2bf(float f) {
  unsigned u = __float_as_uint(f);
  return (unsigned short)((u + 0x7fffu + ((u >> 16) & 1u)) >> 16);  // RNE
}
__device__ __forceinline__ float bf2f(unsigned short h) {
  return __uint_as_float((unsigned)h << 16);
}
__device__ __forceinline__ unsigned char f2fp8(float f) {
  int w = __builtin_amdgcn_cvt_pk_fp8_f32(f, f, 0, false);  // OCP e4m3
  return (unsigned char)(w & 0xff);
}
// decode 4 fp8 bytes of w into acc[0..3] (+=)
__device__ __forceinline__ void fp8x4_acc(int w, float* acc) {
  f32x2 lo = __builtin_amdgcn_cvt_pk_f32_fp8(w, false);
  f32x2 hi = __builtin_amdgcn_cvt_pk_f32_fp8(w, true);
  acc[0] += lo[0]; acc[1] += lo[1]; acc[2] += hi[0]; acc[3] += hi[1];
}

// ---------------- fp32 -> fp8 e4m3 (x scale), 8 elems/thread ----------------
__global__ __launch_bounds__(256) void cvt_fp8(const float* __restrict__ in,
                                               unsigned char* __restrict__ out,
                                               int n, float scale) {
  int i = (blockIdx.x * 256 + threadIdx.x) * 8;
  if (i >= n) return;
  const float4 a = *(const float4*)(in + i);
  const float4 b = *(const float4*)(in + i + 4);
  int w0 = __builtin_amdgcn_cvt_pk_fp8_f32(a.x * scale, a.y * scale, 0, false);
  w0 = __builtin_amdgcn_cvt_pk_fp8_f32(a.z * scale, a.w * scale, w0, true);
  int w1 = __builtin_amdgcn_cvt_pk_fp8_f32(b.x * scale, b.y * scale, 0, false);
  w1 = __builtin_amdgcn_cvt_pk_fp8_f32(b.z * scale, b.w * scale, w1, true);
  *(int2*)(out + i) = make_int2(w0, w1);
}

// ---------------- CSR build ----------------
__global__ __launch_bounds__(256) void zero_i32(int* __restrict__ p, int n) {
  int i = blockIdx.x * 256 + threadIdx.x;
  if (i < n) p[i] = 0;
}

__global__ __launch_bounds__(256) void hist_rows(const int* __restrict__ row,
                                                 int* __restrict__ counts) {
  int e = blockIdx.x * 256 + threadIdx.x;
  if (e < NEDGE) atomicAdd(&counts[row[e]], 1);
}

// exclusive scan of counts[4096] -> starts[4097]; single block of 1024 threads
__global__ __launch_bounds__(1024) void scan4096(const int* __restrict__ counts,
                                                 int* __restrict__ starts) {
  __shared__ int sa[1024], sb[1024];
  const int t = threadIdx.x;
  const int c0 = counts[t * 4], c1 = counts[t * 4 + 1],
            c2 = counts[t * 4 + 2], c3 = counts[t * 4 + 3];
  const int local = c0 + c1 + c2 + c3;
  sa[t] = local;
  __syncthreads();
  int* src = sa; int* dst = sb;
  for (int off = 1; off < 1024; off <<= 1) {
    int v = src[t];
    if (t >= off) v += src[t - off];
    dst[t] = v;
    __syncthreads();
    int* tmp = src; src = dst; dst = tmp;
  }
  const int excl = (t == 0) ? 0 : src[t - 1];
  starts[t * 4]     = excl;
  starts[t * 4 + 1] = excl + c0;
  starts[t * 4 + 2] = excl + c0 + c1;
  starts[t * 4 + 3] = excl + c0 + c1 + c2;
  if (t == 1023) starts[4096] = excl + local;
}

__global__ __launch_bounds__(256) void fill_adj(const int* __restrict__ row,
                                                const int* __restrict__ col,
                                                const int* __restrict__ starts,
                                                int* __restrict__ cursor,
                                                int* __restrict__ adj) {
  int e = blockIdx.x * 256 + threadIdx.x;
  if (e >= NEDGE) return;
  int r = row[e];
  int p = atomicAdd(&cursor[r], 1);
  adj[starts[r] + p] = col[e];
}

// ---- MX fp8 GEMM: C_fp8 = fp8(mul*(A@B^T) [+ ACT_SCALE*bias]) ----
// 128x128 tile, BK=128, 4 waves each 64x64 (4x4 of 16x16x128 MX MFMA,
// unit scales). LDS: granule-split blocks, 16 KB/operand.
__device__ __forceinline__ i32x8 ld_frag(const char* base0) {
  const int4 lo = *(const int4*)(base0);          // orig k quad*32 .. +16
  const int4 hi = *(const int4*)(base0 + 8192);   // orig k quad*32+16 .. +32
  i32x8 f;
  f[0] = lo.x; f[1] = lo.y; f[2] = lo.z; f[3] = lo.w;
  f[4] = hi.x; f[5] = hi.y; f[6] = hi.z; f[7] = hi.w;
  return f;
}

__global__ __launch_bounds__(256) void gemm_mx(
    const unsigned char* __restrict__ A, const unsigned char* __restrict__ B,
    unsigned char* __restrict__ C, int N, int K,
    const float* __restrict__ bias, float mul) {
  __shared__ unsigned char As[128 * 128];  // [As0: 128 rows x 64B][As1: same]
  __shared__ unsigned char Bs[128 * 128];
  const int t = threadIdx.x;
  const int bm = blockIdx.x * 128, bn = blockIdx.y * 128;
  const int wave = t >> 6, lane = t & 63;
  const int wm = (wave >> 1) * 64, wn = (wave & 1) * 64;
  const int m16 = lane & 15, quad = lane >> 4;

  f32x4 acc[4][4] = {};

  // staging: thread t -> row t>>2 (0..63), granule q = t&3.
  // As0 pos (row,q) holds orig granule 2q (byte q*32); As1 holds 2q+1 (+16).
  const int srow = t >> 2;
  const int sg = (t & 3) * 32;
  const unsigned char* Ag0 = A + (size_t)(bm + srow) * K + sg;
  const unsigned char* Ag1 = A + (size_t)(bm + 64 + srow) * K + sg;
  const unsigned char* Bg0 = B + (size_t)(bn + srow) * K + sg;
  const unsigned char* Bg1 = B + (size_t)(bn + 64 + srow) * K + sg;
  char* AsB = (char*)As;
  char* BsB = (char*)Bs;

#define GLDS(gp, lp)                                                       \
  __builtin_amdgcn_global_load_lds(                                        \
      (const __attribute__((address_space(1))) void*)(gp),                 \
      (__attribute__((address_space(3))) void*)(lp), 16, 0, 0)

  for (int kb = 0; kb < K; kb += 128) {
    GLDS(Ag0 + kb,      AsB + t * 16);           // As0 rows 0..63
    GLDS(Ag1 + kb,      AsB + 4096 + t * 16);    // As0 rows 64..127
    GLDS(Ag0 + kb + 16, AsB + 8192 + t * 16);    // As1 rows 0..63
    GLDS(Ag1 + kb + 16, AsB + 12288 + t * 16);   // As1 rows 64..127
    GLDS(Bg0 + kb,      BsB + t * 16);
    GLDS(Bg1 + kb,      BsB + 4096 + t * 16);
    GLDS(Bg0 + kb + 16, BsB + 8192 + t * 16);
    GLDS(Bg1 + kb + 16, BsB + 12288 + t * 16);
    __syncthreads();

    // fragment: lane holds A[m = lane&15][k = quad*32 + j], j=0..31
    i32x8 af[4], bfr[4];
#pragma unroll
    for (int r = 0; r < 4; ++r)
      af[r] = ld_frag(AsB + (wm + r * 16 + m16) * 64 + quad * 16);
#pragma unroll
    for (int c = 0; c < 4; ++c)
      bfr[c] = ld_frag(BsB + (wn + c * 16 + m16) * 64 + quad * 16);
#pragma unroll
    for (int r = 0; r < 4; ++r)
#pragma unroll
      for (int c = 0; c < 4; ++c)
        acc[r][c] = __builtin_amdgcn_mfma_scale_f32_16x16x128_f8f6f4(
            af[r], bfr[c], acc[r][c], 0, 0,      // cbsz=0 (fp8), blgp=0 (fp8)
            0, 0x7f7f7f7f, 0, 0x7f7f7f7f);       // unit E8M0 scales
    __syncthreads();
  }
#undef GLDS

  // C/D layout (16x16 family, shape-determined): col=lane&15, row=quad*4+reg
#pragma unroll
  for (int r = 0; r < 4; ++r) {
#pragma unroll
    for (int c = 0; c < 4; ++c) {
      const int row0 = bm + wm + r * 16 + quad * 4;
      const int col = bn + wn + c * 16 + m16;
      const float bv = bias ? ACT_SCALE * bias[col] : 0.0f;
#pragma unroll
      for (int i = 0; i < 4; ++i) {
        C[(size_t)(row0 + i) * N + col] = f2fp8(acc[r][c][i] * mul + bv);
      }
    }
  }
}

// ---- aggregation (fp8 g in): h = relu(sum g[c]/G_SCALE + b) -> fp8 x ACT ----
__global__ __launch_bounds__(256) void aggr_f8out(
    const unsigned char* __restrict__ g, const int* __restrict__ starts,
    const int* __restrict__ adj, const float* __restrict__ bias,
    unsigned char* __restrict__ hout) {
  const int node = blockIdx.y;
  const int f0 = blockIdx.x * 2048 + threadIdx.x * 8;
  float acc[8] = {0, 0, 0, 0, 0, 0, 0, 0};
  const int s = starts[node], e = starts[node + 1];
  int j = s;
  for (; j + 4 <= e; j += 4) {
    const int c0 = adj[j], c1 = adj[j + 1], c2 = adj[j + 2], c3 = adj[j + 3];
    int2 v0 = *(const int2*)(g + (size_t)c0 * HID_ + f0);
    int2 v1 = *(const int2*)(g + (size_t)c1 * HID_ + f0);
    int2 v2 = *(const int2*)(g + (size_t)c2 * HID_ + f0);
    int2 v3 = *(const int2*)(g + (size_t)c3 * HID_ + f0);
    fp8x4_acc(v0.x, acc);     fp8x4_acc(v0.y, acc + 4);
    fp8x4_acc(v1.x, acc);     fp8x4_acc(v1.y, acc + 4);
    fp8x4_acc(v2.x, acc);     fp8x4_acc(v2.y, acc + 4);
    fp8x4_acc(v3.x, acc);     fp8x4_acc(v3.y, acc + 4);
  }
  for (; j < e; ++j) {
    int2 v = *(const int2*)(g + (size_t)adj[j] * HID_ + f0);
    fp8x4_acc(v.x, acc);      fp8x4_acc(v.y, acc + 4);
  }
  const float4 b0 = *(const float4*)(bias + f0);
  const float4 b1 = *(const float4*)(bias + f0 + 4);
  const float bb[8] = {b0.x, b0.y, b0.z, b0.w, b1.x, b1.y, b1.z, b1.w};
  float v[8];
#pragma unroll
  for (int i = 0; i < 8; ++i)
    v[i] = ACT_SCALE * fmaxf(acc[i] * (1.0f / G_SCALE) + bb[i], 0.0f);
  int w0 = __builtin_amdgcn_cvt_pk_fp8_f32(v[0], v[1], 0, false);
  w0 = __builtin_amdgcn_cvt_pk_fp8_f32(v[2], v[3], w0, true);
  int w1 = __builtin_amdgcn_cvt_pk_fp8_f32(v[4], v[5], 0, false);
  w1 = __builtin_amdgcn_cvt_pk_fp8_f32(v[6], v[7], w1, true);
  *(int2*)(hout + (size_t)node * HID_ + f0) = make_int2(w0, w1);
}

// ---- aggregation variant emitting bf16 (final layer) ----
__global__ __launch_bounds__(256) void aggr_bf16out(
    const unsigned char* __restrict__ g, const int* __restrict__ starts,
    const int* __restrict__ adj, const float* __restrict__ bias,
    unsigned short* __restrict__ hout) {
  const int node = blockIdx.y;
  const int f0 = blockIdx.x * 2048 + threadIdx.x * 8;
  float acc[8] = {0, 0, 0, 0, 0, 0, 0, 0};
  const int s = starts[node], e = starts[node + 1];
  int j = s;
  for (; j + 4 <= e; j += 4) {
    const int c0 = adj[j], c1 = adj[j + 1], c2 = adj[j + 2], c3 = adj[j + 3];
    int2 v0 = *(const int2*)(g + (size_t)c0 * HID_ + f0);
    int2 v1 = *(const int2*)(g + (size_t)c1 * HID_ + f0);
    int2 v2 = *(const int2*)(g + (size_t)c2 * HID_ + f0);
    int2 v3 = *(const int2*)(g + (size_t)c3 * HID_ + f0);
    fp8x4_acc(v0.x, acc);     fp8x4_acc(v0.y, acc + 4);
    fp8x4_acc(v1.x, acc);     fp8x4_acc(v1.y, acc + 4);
    fp8x4_acc(v2.x, acc);     fp8x4_acc(v2.y, acc + 4);
    fp8x4_acc(v3.x, acc);     fp8x4_acc(v3.y, acc + 4);
  }
  for (; j < e; ++j) {
    int2 v = *(const int2*)(g + (size_t)adj[j] * HID_ + f0);
    fp8x4_acc(v.x, acc);      fp8x4_acc(v.y, acc + 4);
  }
  const float4 b0 = *(const float4*)(bias + f0);
  const float4 b1 = *(const float4*)(bias + f0 + 4);
  const float bb[8] = {b0.x, b0.y, b0.z, b0.w, b1.x, b1.y, b1.z, b1.w};
  u16x8 r;
#pragma unroll
  for (int i = 0; i < 8; ++i)
    r[i] = f2bf(fmaxf(acc[i] * (1.0f / G_SCALE) + bb[i], 0.0f));
  *(u16x8*)(hout + (size_t)node * HID_ + f0) = r;
}

// ---------------- hm[row] = mean(h[row,:]) ----------------
__global__ __launch_bounds__(256) void row_mean(const unsigned short* __restrict__ h,
                                                float* __restrict__ hm) {
  const int row = blockIdx.x, t = threadIdx.x;
  const u16x8* p = (const u16x8*)(h + (size_t)row * HID_);
  u16x8 v1 = p[t], v2 = p[t + 256];
  float s = 0.f;
#pragma unroll
  for (int i = 0; i < 8; ++i) s += bf2f(v1[i]) + bf2f(v2[i]);
  for (int off = 32; off > 0; off >>= 1) s += __shfl_down(s, off);
  __shared__ float ws[4];
  if ((t & 63) == 0) ws[t >> 6] = s;
  __syncthreads();
  if (t == 0) hm[row] = (ws[0] + ws[1] + ws[2] + ws[3]) * (1.0f / (float)HID_);
}

// ---------------- z[j] = relu(Wc1[j,:].hm + bc1[j]), one wave per j ----------------
__global__ __launch_bounds__(256) void clf1(const float* __restrict__ Wc1,
                                            const float* __restrict__ bc1,
                                            const float* __restrict__ hm,
                                            float* __restrict__ z) {
  const int wave = threadIdx.x >> 6, lane = threadIdx.x & 63;
  const int j = blockIdx.x * 4 + wave;
  const float* w = Wc1 + (size_t)j * HID_;
  float s = 0.f;
  for (int i = lane; i < HID_; i += 64) s += w[i] * hm[i];
  for (int off = 32; off > 0; off >>= 1) s += __shfl_down(s, off);
  if (lane == 0) z[j] = fmaxf(s + bc1[j], 0.0f);
}

// ---------------- out = Wc2.z + bc2 ----------------
__global__ __launch_bounds__(256) void clf2(const float* __restrict__ Wc2,
                                            const float* __restrict__ bc2,
                                            const float* __restrict__ z,
                                            float* __restrict__ out) {
  const int t = threadIdx.x;
  float s = 0.f;
  for (int i = t; i < HID_ / 2; i += 256) s += z[i] * Wc2[i];
  for (int off = 32; off > 0; off >>= 1) s += __shfl_down(s, off);
  __shared__ float ws[4];
  if ((t & 63) == 0) ws[t >> 6] = s;
  __syncthreads();
  if (t == 0) out[0] = ws[0] + ws[1] + ws[2] + ws[3] + bc2[0];
}

extern "C" void kernel_launch(void* const* d_in, const int* in_sizes, int n_in,
                              void* d_out, int out_size, void* d_ws, size_t ws_size,
                              hipStream_t stream) {
  (void)in_sizes; (void)n_in; (void)out_size; (void)ws_size;
  const float* x       = (const float*)d_in[0];
  const int*   edge    = (const int*)d_in[1];
  const int*   row     = edge;
  const int*   col     = edge + NEDGE;
  const float* W_embed = (const float*)d_in[2];
  const float* b_embed = (const float*)d_in[3];
  const float* W1      = (const float*)d_in[4];
  const float* b1      = (const float*)d_in[5];
  const float* W2      = (const float*)d_in[6];
  const float* b2      = (const float*)d_in[7];
  const float* Wc1     = (const float*)d_in[8];
  const float* bc1     = (const float*)d_in[9];
  const float* Wc2     = (const float*)d_in[10];
  const float* bc2     = (const float*)d_in[11];
  float* out = (float*)d_out;

  char* ws = (char*)d_ws;
  size_t off = 0;
  auto alloc = [&](size_t bytes) {
    char* p = ws + off;
    off += (bytes + 255) & ~(size_t)255;
    return p;
  };
  unsigned char*  xf8  = (unsigned char*)alloc((size_t)N_NODES * IN_DIM_);
  unsigned char*  wef8 = (unsigned char*)alloc((size_t)HID_ * IN_DIM_);
  unsigned char*  w1f8 = (unsigned char*)alloc((size_t)HID_ * HID_);
  unsigned char*  w2f8 = (unsigned char*)alloc((size_t)HID_ * HID_);
  unsigned char*  h0f8 = (unsigned char*)alloc((size_t)N_NODES * HID_);
  unsigned char*  h1f8 = (unsigned char*)alloc((size_t)N_NODES * HID_);
  unsigned char*  g    = (unsigned char*)alloc((size_t)N_NODES * HID_);
  unsigned short* h2   = (unsigned short*)alloc((size_t)N_NODES * HID_ * 2);
  int* counts = (int*)alloc(N_NODES * 4);
  int* cursor = (int*)alloc(N_NODES * 4);
  int* starts = (int*)alloc((N_NODES + 1) * 4);
  int* adj    = (int*)alloc(NEDGE * 4);
  float* hm   = (float*)alloc(N_NODES * 4);
  float* z    = (float*)alloc((HID_ / 2) * 4);

  // CSR build (ws is re-poisoned each call -> must zero)
  zero_i32<<<16, 256, 0, stream>>>(counts, N_NODES);
  zero_i32<<<16, 256, 0, stream>>>(cursor, N_NODES);
  hist_rows<<<NEDGE / 256, 256, 0, stream>>>(row, counts);
  scan4096<<<1, 1024, 0, stream>>>(counts, starts);
  fill_adj<<<NEDGE / 256, 256, 0, stream>>>(row, col, starts, cursor, adj);

  // fp8 conversions (natural order; staging does the granule shuffle)
  cvt_fp8<<<(N_NODES * IN_DIM_ / 8) / 256, 256, 0, stream>>>(x, xf8, N_NODES * IN_DIM_, ACT_SCALE);
  cvt_fp8<<<(HID_ * IN_DIM_ / 8) / 256, 256, 0, stream>>>(W_embed, wef8, HID_ * IN_DIM_, W_SCALE);
  cvt_fp8<<<(HID_ * HID_ / 8) / 256, 256, 0, stream>>>(W1, w1f8, HID_ * HID_, W_SCALE);
  cvt_fp8<<<(HID_ * HID_ / 8) / 256, 256, 0, stream>>>(W2, w2f8, HID_ * HID_, W_SCALE);

  // embed: h0 = fp8(8 * (x @ We^T + be))
  gemm_mx<<<dim3(32, 32), 256, 0, stream>>>(xf8, wef8, h0f8, HID_, IN_DIM_,
                                            b_embed, G_STORE_MUL);
  // layer 1: g = h0 @ W1^T ; h1 = fp8(8 * relu(A g + b1))
  gemm_mx<<<dim3(32, 32), 256, 0, stream>>>(h0f8, w1f8, g, HID_, HID_,
                                            nullptr, G_STORE_MUL);
  aggr_f8out<<<dim3(2, N_NODES), 256, 0, stream>>>(g, starts, adj, b1, h1f8);
  // layer 2: g = h1 @ W2^T ; h2 = relu(A g + b2) (bf16)
  gemm_mx<<<dim3(32, 32), 256, 0, stream>>>(h1f8, w2f8, g, HID_, HID_,
                                            nullptr, G_STORE_MUL);
  aggr_bf16out<<<dim3(2, N_NODES), 256, 0, stream>>>(g, starts, adj, b2, h2);
  // classifier tail
  row_mean<<<N_NODES, 256, 0, stream>>>(h2, hm);
  clf1<<<(HID_ / 2) / 4, 256, 0, stream>>>(Wc1, bc1, hm, z);
  clf2<<<1, 256, 0, stream>>>(Wc2, bc2, z, out);
}